// Round 5
// baseline (265.426 us; speedup 1.0000x reference)
//
#include <hip/hip_runtime.h>
#include <hip/hip_bf16.h>

// Problem constants (PhiAttention: B=2,S=1024,HID=2560,H=32,D=80,ROT=32)
#define Bq 2
#define Sq 1024
#define Tq 2048
#define HIDq 2560
#define Hq 32
#define Dq 80
#define NQKV 7680   // 3*HID

typedef __bf16 bf16x8 __attribute__((ext_vector_type(8)));
typedef float f32x4 __attribute__((ext_vector_type(4)));
typedef unsigned short u16x8 __attribute__((ext_vector_type(8)));
using bf16 = __hip_bfloat16;

__device__ __forceinline__ void gload_lds16(const bf16* g, bf16* l) {
  __builtin_amdgcn_global_load_lds((const __attribute__((address_space(1))) void*)g,
                                   (__attribute__((address_space(3))) void*)l,
                                   16, 0, 0);
}

// ---------------- cast h (fp32 -> bf16) ----------------
__global__ __launch_bounds__(256) void cast_h_kernel(const float* __restrict__ h,
                                                     bf16* __restrict__ hb) {
  int i = (blockIdx.x * 256 + threadIdx.x) * 4;
  float4 v = *(const float4*)(h + i);
  bf16 tmp[4];
  tmp[0] = __float2bfloat16(v.x);
  tmp[1] = __float2bfloat16(v.y);
  tmp[2] = __float2bfloat16(v.z);
  tmp[3] = __float2bfloat16(v.w);
  *(ushort4*)(hb + i) = *(ushort4*)tmp;
}

// ---------------- concat qkv bias ----------------
__global__ __launch_bounds__(256) void bias_concat_kernel(const float* __restrict__ qb,
                                                          const float* __restrict__ kb,
                                                          const float* __restrict__ vb,
                                                          float* __restrict__ bqkv) {
  int i = blockIdx.x * 256 + threadIdx.x;
  if (i < HIDq) bqkv[i] = qb[i];
  else if (i < 2 * HIDq) bqkv[i] = kb[i - HIDq];
  else bqkv[i] = vb[i - 2 * HIDq];
}

// ---------------- transpose-cast weights: wt[n][k] = w[k][n], fp32->bf16 ----------------
__global__ __launch_bounds__(256) void wtrans_kernel(const float* __restrict__ qw,
                                                     const float* __restrict__ kw,
                                                     const float* __restrict__ vw,
                                                     const float* __restrict__ dw,
                                                     bf16* __restrict__ wqkvt,
                                                     bf16* __restrict__ wdt) {
  __shared__ float tile[32][33];
  const int z = blockIdx.z;
  const float* src = (z == 0) ? qw : (z == 1) ? kw : (z == 2) ? vw : dw;
  const int n0 = blockIdx.x * 32;  // src col  (dst row)
  const int k0 = blockIdx.y * 32;  // src row  (dst col)
  const int tx = threadIdx.x, ty = threadIdx.y;
#pragma unroll
  for (int r = 0; r < 4; r++)
    tile[ty + 8 * r][tx] = src[(size_t)(k0 + ty + 8 * r) * HIDq + n0 + tx];
  __syncthreads();
  bf16* dst = (z < 3) ? (wqkvt + (size_t)z * HIDq * HIDq) : wdt;
#pragma unroll
  for (int r = 0; r < 4; r++)
    dst[(size_t)(n0 + ty + 8 * r) * HIDq + k0 + tx] = __float2bfloat16(tile[tx][ty + 8 * r]);
}

// ================= 8-phase 256x256 GEMM (m201 port: T1+T2+T3+T4+T5) =================
// C[M][N] = A[M][K] @ Bt[N][K]^T + bias, bf16 out.  8 waves (2M x 4N), per-wave 128x64.
// BK=64, double-buffered 2x64KB LDS.  K-half staging: half = 256 rows x 32 k (16 KB,
// 2 gload_lds calls).  4 phases per K-tile, each: {stage 1 half || 4-8 ds_read_b128 ->
// barrier -> lgkmcnt(0) -> setprio(1) 16 MFMA setprio(0) -> [vmcnt(10) at k=1,3] -> barrier}.
// Half lifetimes: slot freed exactly one phase before restage (see schedule below).
// FIFO: 1 half staged per phase; needed half always has exactly 5 newer stages in
// flight at its guard point -> s_waitcnt vmcnt(10).  Never 0 except last 2 tiles.
// half index: 0 = A.kc0, 1 = A.kc1, 2 = B.kc0, 3 = B.kc1  (each 16 KB region)
__global__ __launch_bounds__(512, 2) void gemm8p_kernel(const bf16* __restrict__ A,
                                                        const bf16* __restrict__ Bt,
                                                        const float* __restrict__ bias,
                                                        bf16* __restrict__ Cout,
                                                        int N, int K, int tM) {
  __shared__ char smem[131072];  // 2 bufs x (A 32K + B 32K)
  const int tid = threadIdx.x;
  const int lane = tid & 63;
  const int ln = lane & 15, lg = lane >> 4;
  const int wave = tid >> 6;
  const int wm = wave >> 2;   // 0..1
  const int wn = wave & 3;    // 0..3

  // XCD-aware bijective block swizzle (grid % 8 == 0)
  int bid = blockIdx.x, nwg = gridDim.x, swz = bid;
  if ((nwg & 7) == 0) { int cpx = nwg >> 3; swz = (bid & 7) * cpx + (bid >> 3); }
  const int m0 = (swz % tM) * 256;
  const int n0 = (swz / tM) * 256;
  const int NT = K >> 6;  // K / 64

  f32x4 acc[8][4];
  const f32x4 zz = {0.f, 0.f, 0.f, 0.f};
#pragma unroll
  for (int i = 0; i < 8; ++i)
#pragma unroll
    for (int j = 0; j < 4; ++j) acc[i][j] = zz;

  const int Rl0 = tid >> 2;   // row within a 128-row gload call
  const int slot = tid & 3;   // 16B slot in 64B row
  const int wbase = wave * 1024;

  auto STAGE_HALF = [&](int t, int half) {
    const bf16* P = (half < 2) ? A : Bt;
    const int rbase = (half < 2) ? m0 : n0;
    const int k0 = (t << 6) + ((half & 1) << 5);
    char* dst = smem + ((t & 1) * 65536) + half * 16384;
#pragma unroll
    for (int c = 0; c < 2; ++c) {
      const int srow = c * 128 + Rl0;
      const int row = srow ^ ((srow >> 2) & 1);   // involution (bit0 ^= bit2)
      const int col8 = slot ^ (row & 3);          // inverse col swizzle
      gload_lds16(P + (size_t)(rbase + row) * K + k0 + col8 * 8,
                  (bf16*)(dst + c * 8192 + wbase));
    }
  };

  auto FRAG = [&](int buf, int half, int row) -> bf16x8 {
    const char* base = smem + buf * 65536 + half * 16384;
    const unsigned off = ((unsigned)((row ^ ((row >> 2) & 1)) << 6)) |
                         (((unsigned)lg << 4) ^ ((unsigned)(row & 3) << 4));
    return *(const bf16x8*)(base + off);
  };

  // prologue: tile0 all 4 halves + tile1 {B.kc0, A.kc0, B.kc1}; A.kc1(1) comes at (0,k0)
  STAGE_HALF(0, 2); STAGE_HALF(0, 0); STAGE_HALF(0, 3); STAGE_HALF(0, 1);
  STAGE_HALF(1, 2); STAGE_HALF(1, 0); STAGE_HALF(1, 3);
  asm volatile("s_waitcnt vmcnt(10)" ::: "memory");  // oldest 2 stages (tile0 kc0) landed
  __builtin_amdgcn_s_barrier();

  bf16x8 bfr[4];  // B fragments, reused across phase pairs (k0->k1, k2->k3)
  for (int t = 0; t < NT; ++t) {
    const int buf = t & 1;
#pragma unroll
    for (int k = 0; k < 4; ++k) {
      const int kc = k >> 1;   // K-half of this phase
      const int mh = k & 1;    // m-half of this phase
      // stage schedule: each phase stages exactly one half (slot freed last phase)
      if (k == 0)      { if (t + 1 < NT) STAGE_HALF(t + 1, 1); }
      else if (k == 1) { if (t + 2 < NT) STAGE_HALF(t + 2, 2); }
      else if (k == 2) { if (t + 2 < NT) STAGE_HALF(t + 2, 0); }
      else             { if (t + 2 < NT) STAGE_HALF(t + 2, 3); }
      // ds reads: 4 A-frags (+4 B-frags on kc entry)
      bf16x8 af[4];
#pragma unroll
      for (int i = 0; i < 4; ++i)
        af[i] = FRAG(buf, kc, wm * 128 + (mh * 4 + i) * 16 + ln);
      if (mh == 0) {
#pragma unroll
        for (int j = 0; j < 4; ++j)
          bfr[j] = FRAG(buf, 2 + kc, wn * 64 + j * 16 + ln);
      }
      asm volatile("" ::: "memory");
      __builtin_amdgcn_s_barrier();
      asm volatile("s_waitcnt lgkmcnt(0)" ::: "memory");
      __builtin_amdgcn_sched_barrier(0);
      __builtin_amdgcn_s_setprio(1);
#pragma unroll
      for (int i = 0; i < 4; ++i)
#pragma unroll
        for (int j = 0; j < 4; ++j)
          acc[mh * 4 + i][j] =
              __builtin_amdgcn_mfma_f32_16x16x32_bf16(af[i], bfr[j], acc[mh * 4 + i][j], 0, 0, 0);
      __builtin_amdgcn_s_setprio(0);
      if (k == 1 || k == 3) {  // guard next phase's new-half reads
        if (t < NT - 2) asm volatile("s_waitcnt vmcnt(10)" ::: "memory");
        else            asm volatile("s_waitcnt vmcnt(0)" ::: "memory");
      }
      asm volatile("" ::: "memory");
      __builtin_amdgcn_s_barrier();
    }
  }

  // epilogue
#pragma unroll
  for (int j = 0; j < 4; ++j) {
    const int col = n0 + wn * 64 + j * 16 + ln;
    const float bv = bias[col];
#pragma unroll
    for (int i = 0; i < 8; ++i) {
      const int rowb = m0 + wm * 128 + i * 16 + lg * 4;
#pragma unroll
      for (int r = 0; r < 4; ++r)
        Cout[(size_t)(rowb + r) * N + col] = __float2bfloat16(acc[i][j][r] + bv);
    }
  }
}

// ================= pipelined GEMM (dense projection; r4 structure) =================
template <int MFRAG, bool OUT_BF16>
__global__ __launch_bounds__(512, 2) void gemm256_kernel(const bf16* __restrict__ A,
                                                         const bf16* __restrict__ Bt,
                                                         const float* __restrict__ bias,
                                                         void* __restrict__ Cout,
                                                         int N, int K, int tMc) {
  constexpr int ACALLS = MFRAG / 4;
  constexpr int APANEL = 8192 * ACALLS;
  constexpr int BUFSZ = APANEL + 16384;
  __shared__ char smem[3 * BUFSZ];
  const int tid = threadIdx.x;
  const int lane = tid & 63;
  const int ln = lane & 15, lg = lane >> 4;
  const int wave = tid >> 6;
  const int wm = wave >> 2;
  const int wn = wave & 3;

  int bid = blockIdx.x;
  int swz = bid;
  int nwg = gridDim.x;
  if ((nwg & 7) == 0) { int cpx = nwg >> 3; swz = (bid & 7) * cpx + (bid >> 3); }
  const int m0 = (swz % tMc) * (32 * MFRAG);
  const int n0 = (swz / tMc) * 256;

  const int NT = K >> 5;

  f32x4 acc[MFRAG][4];
  const f32x4 zz = {0.f, 0.f, 0.f, 0.f};
#pragma unroll
  for (int i = 0; i < MFRAG; ++i)
#pragma unroll
    for (int j = 0; j < 4; ++j) acc[i][j] = zz;

  const int Rl0 = tid >> 2;
  const int slot = tid & 3;
  const int wbase = (tid >> 6) * 1024;

  auto STAGE = [&](int t, int b) {
    const int k0 = t << 5;
    char* Ab = smem + b * BUFSZ;
    char* Bb = Ab + APANEL;
#pragma unroll
    for (int c = 0; c < ACALLS; ++c) {
      const int srow = c * 128 + Rl0;
      const int row = srow ^ ((srow >> 2) & 1);
      const int col8 = slot ^ (row & 3);
      gload_lds16(A + (size_t)(m0 + row) * K + k0 + col8 * 8,
                  (bf16*)(Ab + c * 8192 + wbase));
    }
#pragma unroll
    for (int c = 0; c < 2; ++c) {
      const int srow = c * 128 + Rl0;
      const int row = srow ^ ((srow >> 2) & 1);
      const int col8 = slot ^ (row & 3);
      gload_lds16(Bt + (size_t)(n0 + row) * K + k0 + col8 * 8,
                  (bf16*)(Bb + c * 8192 + wbase));
    }
  };

  auto FRAG = [&](const char* base, int row) -> bf16x8 {
    const unsigned off = ((unsigned)((row ^ ((row >> 2) & 1)) << 6)) |
                         (((unsigned)lg << 4) ^ ((unsigned)(row & 3) << 4));
    return *(const bf16x8*)(base + off);
  };

  auto WAIT_COUNTED = [&]() {
    if constexpr (ACALLS == 2) asm volatile("s_waitcnt vmcnt(4)" ::: "memory");
    else                       asm volatile("s_waitcnt vmcnt(3)" ::: "memory");
  };

  STAGE(0, 0);
  STAGE(1, 1);
  WAIT_COUNTED();
  __builtin_amdgcn_s_barrier();

  for (int t = 0; t < NT; ++t) {
    const int cb = t % 3;
    const char* Ab = smem + cb * BUFSZ;
    const char* Bb = Ab + APANEL;
    if (t + 2 < NT) STAGE(t + 2, (t + 2) % 3);

    bf16x8 bfr[4];
#pragma unroll
    for (int j = 0; j < 4; ++j) bfr[j] = FRAG(Bb, wn * 64 + j * 16 + ln);
#pragma unroll
    for (int ph = 0; ph < ACALLS; ++ph) {
      bf16x8 af[4];
#pragma unroll
      for (int i = 0; i < 4; ++i)
        af[i] = FRAG(Ab, wm * (16 * MFRAG) + (ph * 4 + i) * 16 + ln);
      __builtin_amdgcn_s_setprio(1);
#pragma unroll
      for (int i = 0; i < 4; ++i)
#pragma unroll
        for (int j = 0; j < 4; ++j)
          acc[ph * 4 + i][j] =
              __builtin_amdgcn_mfma_f32_16x16x32_bf16(af[i], bfr[j], acc[ph * 4 + i][j], 0, 0, 0);
      __builtin_amdgcn_s_setprio(0);
    }

    if (t + 2 < NT) WAIT_COUNTED();
    else            asm volatile("s_waitcnt vmcnt(0)" ::: "memory");
    __builtin_amdgcn_s_barrier();
  }

#pragma unroll
  for (int j = 0; j < 4; ++j) {
    const int col = n0 + wn * 64 + j * 16 + ln;
    const float bv = bias[col];
#pragma unroll
    for (int i = 0; i < MFRAG; ++i) {
      const int rowb = m0 + wm * (16 * MFRAG) + i * 16 + lg * 4;
#pragma unroll
      for (int r = 0; r < 4; ++r) {
        const float v = acc[i][j][r] + bv;
        if (OUT_BF16)
          ((bf16*)Cout)[(size_t)(rowb + r) * N + col] = __float2bfloat16(v);
        else
          ((float*)Cout)[(size_t)(rowb + r) * N + col] = v;
      }
    }
  }
}

// ---------------- RoPE on q and k (in-place, bf16) ----------------
__global__ __launch_bounds__(256) void rope_kernel(bf16* __restrict__ qkv,
                                                   const int* __restrict__ positions) {
  int tid = blockIdx.x * 256 + threadIdx.x;  // T*H*16
  int i = tid & 15;
  int h = (tid >> 4) & 31;
  int t = tid >> 9;
  float pos = (float)positions[t];
  float inv = exp2f(-0.83048202372f * (float)i);  // 10000^(-2i/32)
  float ang = pos * inv;
  float s, c;
  sincosf(ang, &s, &c);
  size_t base = (size_t)t * NQKV + h * Dq + i;
  {
    float x1 = __bfloat162float(qkv[base]);
    float x2 = __bfloat162float(qkv[base + 16]);
    qkv[base] = __float2bfloat16(x1 * c - x2 * s);
    qkv[base + 16] = __float2bfloat16(x2 * c + x1 * s);
  }
  base += HIDq;
  {
    float x1 = __bfloat162float(qkv[base]);
    float x2 = __bfloat162float(qkv[base + 16]);
    qkv[base] = __float2bfloat16(x1 * c - x2 * s);
    qkv[base + 16] = __float2bfloat16(x2 * c + x1 * s);
  }
}

// ---------------- V transpose: vT[b][hd][s] = v[b*S+s][hd] ----------------
__global__ __launch_bounds__(256) void vtrans_kernel(const bf16* __restrict__ qkv,
                                                     bf16* __restrict__ vT) {
  __shared__ bf16 tile[32][33];
  const int b = blockIdx.z;
  const int c0 = blockIdx.x * 32;  // hd
  const int s0 = blockIdx.y * 32;  // s
  const int tx = threadIdx.x, ty = threadIdx.y;
#pragma unroll
  for (int r = 0; r < 4; r++)
    tile[ty + 8 * r][tx] = qkv[(size_t)(b * Sq + s0 + ty + 8 * r) * NQKV + 2 * HIDq + c0 + tx];
  __syncthreads();
#pragma unroll
  for (int r = 0; r < 4; r++)
    vT[(size_t)b * HIDq * Sq + (size_t)(c0 + ty + 8 * r) * Sq + s0 + tx] = tile[tx][ty + 8 * r];
}

// ---------------- causal flash attention (balanced, QBLK=64, paired q-tiles) ----
__global__ __launch_bounds__(256) void attn_kernel(const bf16* __restrict__ qkv,
                                                   const bf16* __restrict__ vT,
                                                   bf16* __restrict__ obuf) {
  const int p = blockIdx.x;
  const int h = blockIdx.y;
  const int b = blockIdx.z;
  __shared__ bf16 Ks[64][104];     // pad: 208B rows -> 2-way (free)
  __shared__ bf16 Vt[80][72];      // pad: 144B rows -> 2-way (free)
  __shared__ bf16 Ps[4][16][72];
  const int tid = threadIdx.x;
  const int wave = tid >> 6, lane = tid & 63;
  const int ln = lane & 15, lg = lane >> 4;
  const float scale = 0.1118033988749895f;  // 1/sqrt(80)
  const u16x8 zv = {0, 0, 0, 0, 0, 0, 0, 0};

#pragma unroll
  for (int qsel = 0; qsel < 2; ++qsel) {
    const int qt = qsel ? (15 - p) : p;

    bf16x8 aq[3];
    {
      const size_t qbase = (size_t)(b * Sq + qt * 64 + wave * 16 + ln) * NQKV + h * Dq;
#pragma unroll
      for (int kc = 0; kc < 3; ++kc) {
        const int col = kc * 32 + lg * 8;
        u16x8 v = zv;
        if (col < 80) v = *(const u16x8*)(qkv + qbase + col);
        aq[kc] = *(bf16x8*)&v;
      }
    }

    float mstate[4], lstate[4];
    f32x4 oacc[5];
    const f32x4 zz = {0.f, 0.f, 0.f, 0.f};
#pragma unroll
    for (int r = 0; r < 4; ++r) { mstate[r] = -__builtin_inff(); lstate[r] = 0.f; }
#pragma unroll
    for (int n = 0; n < 5; ++n) oacc[n] = zz;

    for (int j = 0; j <= qt; ++j) {
      const int kv0 = j * 64;
      __syncthreads();
      for (int idx = tid; idx < 64 * 13; idx += 256) {
        int rr = idx / 13, c8 = idx % 13;
        u16x8 val = zv;
        if (c8 < 10)
          val = *(const u16x8*)(qkv + (size_t)(b * Sq + kv0 + rr) * NQKV + HIDq + h * Dq + c8 * 8);
        *(u16x8*)&Ks[rr][c8 * 8] = val;
      }
      for (int idx = tid; idx < 80 * 8; idx += 256) {
        int rr = idx >> 3, c8 = idx & 7;
        *(u16x8*)&Vt[rr][c8 * 8] =
            *(const u16x8*)(vT + (size_t)b * HIDq * Sq + (size_t)(h * Dq + rr) * Sq + kv0 + c8 * 8);
      }
      __syncthreads();

      f32x4 sacc[4];
#pragma unroll
      for (int n = 0; n < 4; ++n) sacc[n] = zz;
#pragma unroll
      for (int kc = 0; kc < 3; ++kc) {
        bf16x8 bk[4];
#pragma unroll
        for (int n = 0; n < 4; ++n) bk[n] = *(const bf16x8*)&Ks[n * 16 + ln][kc * 32 + lg * 8];
#pragma unroll
        for (int n = 0; n < 4; ++n)
          sacc[n] = __builtin_amdgcn_mfma_f32_16x16x32_bf16(aq[kc], bk[n], sacc[n], 0, 0, 0);
      }

      const bool diag = (j == qt);
#pragma unroll
      for (int r = 0; r < 4; ++r) {
        const int qloc = wave * 16 + lg * 4 + r;
        float v[4];
        float vmax = -__builtin_inff();
#pragma unroll
        for (int n = 0; n < 4; ++n) {
          float x = sacc[n][r] * scale;
          if (diag && (n * 16 + ln) > qloc) x = -__builtin_inff();
          v[n] = x;
          vmax = fmaxf(vmax, x);
        }
#pragma unroll
        for (int off = 8; off >= 1; off >>= 1) vmax = fmaxf(vmax, __shfl_xor(vmax, off, 64));
        const float mo = mstate[r];
        const float mn = fmaxf(mo, vmax);
        const float alpha = __expf(mo - mn);
        float psum = 0.f;
#pragma unroll
        for (int n = 0; n < 4; ++n) {
          const float pv = __expf(v[n] - mn);
          psum += pv;
          Ps[wave][lg * 4 + r][n * 16 + ln] = __float2bfloat16(pv);
        }
#pragma unroll
        for (int off = 8; off >= 1; off >>= 1) psum += __shfl_xor(psum, off, 64);
        lstate[r] = lstate[r] * alpha + psum;
        mstate[r] = mn;
#pragma unroll
        for (int n5 = 0; n5 < 5; ++n5) oacc[n5][r] *= alpha;
      }
      asm volatile("s_waitcnt lgkmcnt(0)" ::: "memory");
      __builtin_amdgcn_sched_barrier(0);

#pragma unroll
      for (int kc = 0; kc < 2; ++kc) {
        bf16x8 ap = *(const bf16x8*)&Ps[wave][ln][kc * 32 + lg * 8];
        bf16x8 bv[5];
#pragma unroll
        for (int n = 0; n < 5; ++n) bv[n] = *(const bf16x8*)&Vt[n * 16 + ln][kc * 32 + lg * 8];
#pragma unroll
        for (int n = 0; n < 5; ++n)
          oacc[n] = __builtin_amdgcn_mfma_f32_16x16x32_bf16(ap, bv[n], oacc[n], 0, 0, 0);
      }
    }

#pragma unroll
    for (int r = 0; r < 4; ++r) {
      const float inv = 1.0f / lstate[r];
      const size_t rowbase =
          (size_t)(b * Sq + qt * 64 + wave * 16 + lg * 4 + r) * HIDq + h * Dq;
#pragma unroll
      for (int n5 = 0; n5 < 5; ++n5)
        obuf[rowbase + n5 * 16 + ln] = __float2bfloat16(oacc[n5][r] * inv);
    }
  }
}

// ---------------- launch ----------------
extern "C" void kernel_launch(void* const* d_in, const int* in_sizes, int n_in,
                              void* d_out, int out_size, void* d_ws, size_t ws_size,
                              hipStream_t stream) {
  const float* h = (const float*)d_in[0];
  const float* q_w = (const float*)d_in[3];
  const float* q_b = (const float*)d_in[4];
  const float* k_w = (const float*)d_in[5];
  const float* k_b = (const float*)d_in[6];
  const float* v_w = (const float*)d_in[7];
  const float* v_b = (const float*)d_in[8];
  const float* dw = (const float*)d_in[9];
  const float* db = (const float*)d_in[10];
  const int* positions = (const int*)d_in[11];

  if (ws_size < 94402560ull) return;
  char* ws = (char*)d_ws;
  bf16* hb = (bf16*)(ws);                    // 10,485,760
  bf16* wqkvt = (bf16*)(ws + 10485760);      // 39,321,600
  bf16* wdt = (bf16*)(ws + 49807360);        // 13,107,200
  bf16* qkv = (bf16*)(ws + 62914560);        // 31,457,280
  float* bqkv = (float*)(ws + 94371840);     // 30,720
  bf16* vT = hb;       // h dead after QKV gemm
  bf16* obuf = wqkvt;  // qkv weights dead after QKV gemm

  cast_h_kernel<<<5120, 256, 0, stream>>>(h, hb);
  bias_concat_kernel<<<30, 256, 0, stream>>>(q_b, k_b, v_b, bqkv);
  wtrans_kernel<<<dim3(80, 80, 4), dim3(32, 8), 0, stream>>>(q_w, k_w, v_w, dw, wqkvt, wdt);
  // QKV GEMM: 8-phase 256x256 tiles -> 8 x 30 = 240 blocks
  gemm8p_kernel<<<240, 512, 0, stream>>>(hb, wqkvt, bqkv, qkv, NQKV, HIDq, 8);
  rope_kernel<<<4096, 256, 0, stream>>>(qkv, positions);
  vtrans_kernel<<<dim3(80, 32, 2), dim3(32, 8), 0, stream>>>(qkv, vT);
  attn_kernel<<<dim3(8, 32, 2), 256, 0, stream>>>(qkv, vT, obuf);
  // dense GEMM: 128x256 tiles -> 16 x 10 = 160 blocks
  gemm256_kernel<4, false><<<160, 512, 0, stream>>>(obuf, wdt, db, d_out, HIDq, HIDq, 16);
}

// Round 6
// 262.080 us; speedup vs baseline: 1.0128x; 1.0128x over previous
//
#include <hip/hip_runtime.h>
#include <hip/hip_bf16.h>

// Problem constants (PhiAttention: B=2,S=1024,HID=2560,H=32,D=80,ROT=32)
#define Bq 2
#define Sq 1024
#define Tq 2048
#define HIDq 2560
#define Hq 32
#define Dq 80
#define NQKV 7680   // 3*HID

typedef __bf16 bf16x8 __attribute__((ext_vector_type(8)));
typedef float f32x4 __attribute__((ext_vector_type(4)));
typedef unsigned short u16x8 __attribute__((ext_vector_type(8)));
using bf16 = __hip_bfloat16;

__device__ __forceinline__ void gload_lds16(const bf16* g, bf16* l) {
  __builtin_amdgcn_global_load_lds((const __attribute__((address_space(1))) void*)g,
                                   (__attribute__((address_space(3))) void*)l,
                                   16, 0, 0);
}

// ---------------- cast h (fp32 -> bf16) ----------------
__global__ __launch_bounds__(256) void cast_h_kernel(const float* __restrict__ h,
                                                     bf16* __restrict__ hb) {
  int i = (blockIdx.x * 256 + threadIdx.x) * 4;
  float4 v = *(const float4*)(h + i);
  bf16 tmp[4];
  tmp[0] = __float2bfloat16(v.x);
  tmp[1] = __float2bfloat16(v.y);
  tmp[2] = __float2bfloat16(v.z);
  tmp[3] = __float2bfloat16(v.w);
  *(ushort4*)(hb + i) = *(ushort4*)tmp;
}

// ---------------- concat qkv bias ----------------
__global__ __launch_bounds__(256) void bias_concat_kernel(const float* __restrict__ qb,
                                                          const float* __restrict__ kb,
                                                          const float* __restrict__ vb,
                                                          float* __restrict__ bqkv) {
  int i = blockIdx.x * 256 + threadIdx.x;
  if (i < HIDq) bqkv[i] = qb[i];
  else if (i < 2 * HIDq) bqkv[i] = kb[i - HIDq];
  else bqkv[i] = vb[i - 2 * HIDq];
}

// ---------------- transpose-cast weights: wt[n][k] = w[k][n], fp32->bf16 ----------------
__global__ __launch_bounds__(256) void wtrans_kernel(const float* __restrict__ qw,
                                                     const float* __restrict__ kw,
                                                     const float* __restrict__ vw,
                                                     const float* __restrict__ dw,
                                                     bf16* __restrict__ wqkvt,
                                                     bf16* __restrict__ wdt) {
  __shared__ float tile[32][33];
  const int z = blockIdx.z;
  const float* src = (z == 0) ? qw : (z == 1) ? kw : (z == 2) ? vw : dw;
  const int n0 = blockIdx.x * 32;  // src col  (dst row)
  const int k0 = blockIdx.y * 32;  // src row  (dst col)
  const int tx = threadIdx.x, ty = threadIdx.y;
#pragma unroll
  for (int r = 0; r < 4; r++)
    tile[ty + 8 * r][tx] = src[(size_t)(k0 + ty + 8 * r) * HIDq + n0 + tx];
  __syncthreads();
  bf16* dst = (z < 3) ? (wqkvt + (size_t)z * HIDq * HIDq) : wdt;
#pragma unroll
  for (int r = 0; r < 4; r++)
    dst[(size_t)(n0 + ty + 8 * r) * HIDq + k0 + tx] = __float2bfloat16(tile[tx][ty + 8 * r]);
}

// ================= pipelined ring GEMM (T1+T2+T4+T5), occupancy-tuned =================
// C[M][N] = A[M][K] @ Bt[N][K]^T + bias.  8 waves (2M x 4N).
// Tile = (32*MFRAG) x (64*NFRAG); per-wave C = (16*MFRAG) x (16*NFRAG).
// BK=32, 3-buffer LDS ring, counted vmcnt, raw s_barrier, XOR swizzle
// (pre-swizzled global source + swizzled ds_read — both-sides, rule 21).
// Sized for >=2 blocks/CU: MFRAG=4,NFRAG=4 -> 72 KB LDS; launch_bounds(512,4)
// caps VGPR at 128 so 2 blocks co-reside -> inter-block MFMA/LDS-drain overlap.
template <int MFRAG, int NFRAG, bool OUT_BF16>
__global__ __launch_bounds__(512, 4) void gemm256_kernel(const bf16* __restrict__ A,
                                                         const bf16* __restrict__ Bt,
                                                         const float* __restrict__ bias,
                                                         void* __restrict__ Cout,
                                                         int N, int K, int tMc) {
  constexpr int ACALLS = MFRAG / 4;        // global_load_lds calls for the A panel
  constexpr int BCALLS = NFRAG / 2;        // and for the B panel
  constexpr int APANEL = 8192 * ACALLS;    // bytes
  constexpr int BUFSZ = APANEL + 8192 * BCALLS;
  __shared__ char smem[3 * BUFSZ];
  const int tid = threadIdx.x;
  const int lane = tid & 63;
  const int ln = lane & 15, lg = lane >> 4;
  const int wave = tid >> 6;
  const int wm = wave >> 2;   // 0..1
  const int wn = wave & 3;    // 0..3

  // XCD-aware bijective block swizzle (grids are multiples of 8)
  int bid = blockIdx.x;
  int swz = bid;
  int nwg = gridDim.x;
  if ((nwg & 7) == 0) { int cpx = nwg >> 3; swz = (bid & 7) * cpx + (bid >> 3); }
  const int m0 = (swz % tMc) * (32 * MFRAG);
  const int n0 = (swz / tMc) * (64 * NFRAG);

  const int NT = K >> 5;  // K / 32

  f32x4 acc[MFRAG][NFRAG];
  const f32x4 zz = {0.f, 0.f, 0.f, 0.f};
#pragma unroll
  for (int i = 0; i < MFRAG; ++i)
#pragma unroll
    for (int j = 0; j < NFRAG; ++j) acc[i][j] = zz;

  const int Rl0 = tid >> 2;        // stored-row within an 8KB call (0..127)
  const int slot = tid & 3;        // 16B slot within the 64B row
  const int wbase = (tid >> 6) * 1024;

  auto STAGE = [&](int t, int b) {
    const int k0 = t << 5;
    char* Ab = smem + b * BUFSZ;
    char* Bb = Ab + APANEL;
#pragma unroll
    for (int c = 0; c < ACALLS; ++c) {
      const int srow = c * 128 + Rl0;
      const int row = srow ^ ((srow >> 2) & 1);
      const int col8 = slot ^ (row & 3);
      gload_lds16(A + (size_t)(m0 + row) * K + k0 + col8 * 8,
                  (bf16*)(Ab + c * 8192 + wbase));
    }
#pragma unroll
    for (int c = 0; c < BCALLS; ++c) {
      const int srow = c * 128 + Rl0;
      const int row = srow ^ ((srow >> 2) & 1);
      const int col8 = slot ^ (row & 3);
      gload_lds16(Bt + (size_t)(n0 + row) * K + k0 + col8 * 8,
                  (bf16*)(Bb + c * 8192 + wbase));
    }
  };

  auto FRAG = [&](const char* base, int row) -> bf16x8 {
    const unsigned off = ((unsigned)((row ^ ((row >> 2) & 1)) << 6)) |
                         (((unsigned)lg << 4) ^ ((unsigned)(row & 3) << 4));
    return *(const bf16x8*)(base + off);
  };

  auto WAIT_COUNTED = [&]() {
    constexpr int NCALLS = ACALLS + BCALLS;
    if constexpr (NCALLS == 2)      asm volatile("s_waitcnt vmcnt(2)" ::: "memory");
    else if constexpr (NCALLS == 3) asm volatile("s_waitcnt vmcnt(3)" ::: "memory");
    else                            asm volatile("s_waitcnt vmcnt(4)" ::: "memory");
  };

  STAGE(0, 0);
  STAGE(1, 1);
  WAIT_COUNTED();
  __builtin_amdgcn_s_barrier();

  for (int t = 0; t < NT; ++t) {
    const int cb = t % 3;
    const char* Ab = smem + cb * BUFSZ;
    const char* Bb = Ab + APANEL;
    if (t + 2 < NT) STAGE(t + 2, (t + 2) % 3);

    bf16x8 bfr[NFRAG];
#pragma unroll
    for (int j = 0; j < NFRAG; ++j) bfr[j] = FRAG(Bb, wn * (16 * NFRAG) + j * 16 + ln);
#pragma unroll
    for (int ph = 0; ph < ACALLS; ++ph) {
      bf16x8 af[4];
#pragma unroll
      for (int i = 0; i < 4; ++i)
        af[i] = FRAG(Ab, wm * (16 * MFRAG) + (ph * 4 + i) * 16 + ln);
      __builtin_amdgcn_s_setprio(1);
#pragma unroll
      for (int i = 0; i < 4; ++i)
#pragma unroll
        for (int j = 0; j < NFRAG; ++j)
          acc[ph * 4 + i][j] =
              __builtin_amdgcn_mfma_f32_16x16x32_bf16(af[i], bfr[j], acc[ph * 4 + i][j], 0, 0, 0);
      __builtin_amdgcn_s_setprio(0);
    }

    if (t + 2 < NT) WAIT_COUNTED();
    else            asm volatile("s_waitcnt vmcnt(0)" ::: "memory");
    __builtin_amdgcn_s_barrier();
  }

  // epilogue — j innermost so the NFRAG partial-line stores per row merge in L2
#pragma unroll
  for (int i = 0; i < MFRAG; ++i) {
    const int rowb = m0 + wm * (16 * MFRAG) + i * 16 + lg * 4;
#pragma unroll
    for (int r = 0; r < 4; ++r) {
#pragma unroll
      for (int j = 0; j < NFRAG; ++j) {
        const int col = n0 + wn * (16 * NFRAG) + j * 16 + ln;
        const float v = acc[i][j][r] + bias[col];
        if (OUT_BF16)
          ((bf16*)Cout)[(size_t)(rowb + r) * N + col] = __float2bfloat16(v);
        else
          ((float*)Cout)[(size_t)(rowb + r) * N + col] = v;
      }
    }
  }
}

// ---------------- RoPE on q and k (in-place, bf16) ----------------
__global__ __launch_bounds__(256) void rope_kernel(bf16* __restrict__ qkv,
                                                   const int* __restrict__ positions) {
  int tid = blockIdx.x * 256 + threadIdx.x;  // T*H*16
  int i = tid & 15;
  int h = (tid >> 4) & 31;
  int t = tid >> 9;
  float pos = (float)positions[t];
  float inv = exp2f(-0.83048202372f * (float)i);  // 10000^(-2i/32)
  float ang = pos * inv;
  float s, c;
  sincosf(ang, &s, &c);
  size_t base = (size_t)t * NQKV + h * Dq + i;
  {
    float x1 = __bfloat162float(qkv[base]);
    float x2 = __bfloat162float(qkv[base + 16]);
    qkv[base] = __float2bfloat16(x1 * c - x2 * s);
    qkv[base + 16] = __float2bfloat16(x2 * c + x1 * s);
  }
  base += HIDq;
  {
    float x1 = __bfloat162float(qkv[base]);
    float x2 = __bfloat162float(qkv[base + 16]);
    qkv[base] = __float2bfloat16(x1 * c - x2 * s);
    qkv[base + 16] = __float2bfloat16(x2 * c + x1 * s);
  }
}

// ---------------- V transpose: vT[b][hd][s] = v[b*S+s][hd] ----------------
__global__ __launch_bounds__(256) void vtrans_kernel(const bf16* __restrict__ qkv,
                                                     bf16* __restrict__ vT) {
  __shared__ bf16 tile[32][33];
  const int b = blockIdx.z;
  const int c0 = blockIdx.x * 32;  // hd
  const int s0 = blockIdx.y * 32;  // s
  const int tx = threadIdx.x, ty = threadIdx.y;
#pragma unroll
  for (int r = 0; r < 4; r++)
    tile[ty + 8 * r][tx] = qkv[(size_t)(b * Sq + s0 + ty + 8 * r) * NQKV + 2 * HIDq + c0 + tx];
  __syncthreads();
#pragma unroll
  for (int r = 0; r < 4; r++)
    vT[(size_t)b * HIDq * Sq + (size_t)(c0 + ty + 8 * r) * Sq + s0 + tx] = tile[tx][ty + 8 * r];
}

// ---------------- causal flash attention (balanced, QBLK=64, paired q-tiles) ----
// grid (8 pairs, 32 h, 2 b), 256 threads (4 waves x 16 q-rows).
// Block p handles q-tiles p and 15-p  -> exactly 17 KV-tile units per block.
// Q fragments live in registers; K/V staged in padded LDS (2-way conflicts only).
__global__ __launch_bounds__(256) void attn_kernel(const bf16* __restrict__ qkv,
                                                   const bf16* __restrict__ vT,
                                                   bf16* __restrict__ obuf) {
  const int p = blockIdx.x;
  const int h = blockIdx.y;
  const int b = blockIdx.z;
  __shared__ bf16 Ks[64][104];     // pad: 208B rows -> 2-way (free)
  __shared__ bf16 Vt[80][72];      // pad: 144B rows -> 2-way (free)
  __shared__ bf16 Ps[4][16][72];
  const int tid = threadIdx.x;
  const int wave = tid >> 6, lane = tid & 63;
  const int ln = lane & 15, lg = lane >> 4;
  const float scale = 0.1118033988749895f;  // 1/sqrt(80)
  const u16x8 zv = {0, 0, 0, 0, 0, 0, 0, 0};

#pragma unroll
  for (int qsel = 0; qsel < 2; ++qsel) {
    const int qt = qsel ? (15 - p) : p;

    bf16x8 aq[3];
    {
      const size_t qbase = (size_t)(b * Sq + qt * 64 + wave * 16 + ln) * NQKV + h * Dq;
#pragma unroll
      for (int kc = 0; kc < 3; ++kc) {
        const int col = kc * 32 + lg * 8;
        u16x8 v = zv;
        if (col < 80) v = *(const u16x8*)(qkv + qbase + col);
        aq[kc] = *(bf16x8*)&v;
      }
    }

    float mstate[4], lstate[4];
    f32x4 oacc[5];
    const f32x4 zz = {0.f, 0.f, 0.f, 0.f};
#pragma unroll
    for (int r = 0; r < 4; ++r) { mstate[r] = -__builtin_inff(); lstate[r] = 0.f; }
#pragma unroll
    for (int n = 0; n < 5; ++n) oacc[n] = zz;

    for (int j = 0; j <= qt; ++j) {
      const int kv0 = j * 64;
      __syncthreads();
      for (int idx = tid; idx < 64 * 13; idx += 256) {
        int rr = idx / 13, c8 = idx % 13;
        u16x8 val = zv;
        if (c8 < 10)
          val = *(const u16x8*)(qkv + (size_t)(b * Sq + kv0 + rr) * NQKV + HIDq + h * Dq + c8 * 8);
        *(u16x8*)&Ks[rr][c8 * 8] = val;
      }
      for (int idx = tid; idx < 80 * 8; idx += 256) {
        int rr = idx >> 3, c8 = idx & 7;
        *(u16x8*)&Vt[rr][c8 * 8] =
            *(const u16x8*)(vT + (size_t)b * HIDq * Sq + (size_t)(h * Dq + rr) * Sq + kv0 + c8 * 8);
      }
      __syncthreads();

      f32x4 sacc[4];
#pragma unroll
      for (int n = 0; n < 4; ++n) sacc[n] = zz;
#pragma unroll
      for (int kc = 0; kc < 3; ++kc) {
        bf16x8 bk[4];
#pragma unroll
        for (int n = 0; n < 4; ++n) bk[n] = *(const bf16x8*)&Ks[n * 16 + ln][kc * 32 + lg * 8];
#pragma unroll
        for (int n = 0; n < 4; ++n)
          sacc[n] = __builtin_amdgcn_mfma_f32_16x16x32_bf16(aq[kc], bk[n], sacc[n], 0, 0, 0);
      }

      const bool diag = (j == qt);
#pragma unroll
      for (int r = 0; r < 4; ++r) {
        const int qloc = wave * 16 + lg * 4 + r;
        float v[4];
        float vmax = -__builtin_inff();
#pragma unroll
        for (int n = 0; n < 4; ++n) {
          float x = sacc[n][r] * scale;
          if (diag && (n * 16 + ln) > qloc) x = -__builtin_inff();
          v[n] = x;
          vmax = fmaxf(vmax, x);
        }
#pragma unroll
        for (int off = 8; off >= 1; off >>= 1) vmax = fmaxf(vmax, __shfl_xor(vmax, off, 64));
        const float mo = mstate[r];
        const float mn = fmaxf(mo, vmax);
        const float alpha = __expf(mo - mn);
        float psum = 0.f;
#pragma unroll
        for (int n = 0; n < 4; ++n) {
          const float pv = __expf(v[n] - mn);
          psum += pv;
          Ps[wave][lg * 4 + r][n * 16 + ln] = __float2bfloat16(pv);
        }
#pragma unroll
        for (int off = 8; off >= 1; off >>= 1) psum += __shfl_xor(psum, off, 64);
        lstate[r] = lstate[r] * alpha + psum;
        mstate[r] = mn;
#pragma unroll
        for (int n5 = 0; n5 < 5; ++n5) oacc[n5][r] *= alpha;
      }
      asm volatile("s_waitcnt lgkmcnt(0)" ::: "memory");
      __builtin_amdgcn_sched_barrier(0);

#pragma unroll
      for (int kc = 0; kc < 2; ++kc) {
        bf16x8 ap = *(const bf16x8*)&Ps[wave][ln][kc * 32 + lg * 8];
        bf16x8 bv[5];
#pragma unroll
        for (int n = 0; n < 5; ++n) bv[n] = *(const bf16x8*)&Vt[n * 16 + ln][kc * 32 + lg * 8];
#pragma unroll
        for (int n = 0; n < 5; ++n)
          oacc[n] = __builtin_amdgcn_mfma_f32_16x16x32_bf16(ap, bv[n], oacc[n], 0, 0, 0);
      }
    }

#pragma unroll
    for (int r = 0; r < 4; ++r) {
      const float inv = 1.0f / lstate[r];
      const size_t rowbase =
          (size_t)(b * Sq + qt * 64 + wave * 16 + lg * 4 + r) * HIDq + h * Dq;
#pragma unroll
      for (int n5 = 0; n5 < 5; ++n5)
        obuf[rowbase + n5 * 16 + ln] = __float2bfloat16(oacc[n5][r] * inv);
    }
  }
}

// ---------------- launch ----------------
extern "C" void kernel_launch(void* const* d_in, const int* in_sizes, int n_in,
                              void* d_out, int out_size, void* d_ws, size_t ws_size,
                              hipStream_t stream) {
  const float* h = (const float*)d_in[0];
  const float* q_w = (const float*)d_in[3];
  const float* q_b = (const float*)d_in[4];
  const float* k_w = (const float*)d_in[5];
  const float* k_b = (const float*)d_in[6];
  const float* v_w = (const float*)d_in[7];
  const float* v_b = (const float*)d_in[8];
  const float* dw = (const float*)d_in[9];
  const float* db = (const float*)d_in[10];
  const int* positions = (const int*)d_in[11];

  if (ws_size < 94402560ull) return;
  char* ws = (char*)d_ws;
  bf16* hb = (bf16*)(ws);                    // 10,485,760
  bf16* wqkvt = (bf16*)(ws + 10485760);      // 39,321,600
  bf16* wdt = (bf16*)(ws + 49807360);        // 13,107,200
  bf16* qkv = (bf16*)(ws + 62914560);        // 31,457,280
  float* bqkv = (float*)(ws + 94371840);     // 30,720
  bf16* vT = hb;       // h dead after QKV gemm
  bf16* obuf = wqkvt;  // qkv weights dead after QKV gemm

  cast_h_kernel<<<5120, 256, 0, stream>>>(h, hb);
  bias_concat_kernel<<<30, 256, 0, stream>>>(q_b, k_b, v_b, bqkv);
  wtrans_kernel<<<dim3(80, 80, 4), dim3(32, 8), 0, stream>>>(q_w, k_w, v_w, dw, wqkvt, wdt);
  // QKV GEMM: 128x256 tiles -> 16 x 30 = 480 blocks (~2 blocks/CU)
  gemm256_kernel<4, 4, true><<<480, 512, 0, stream>>>(hb, wqkvt, bqkv, qkv, NQKV, HIDq, 16);
  rope_kernel<<<4096, 256, 0, stream>>>(qkv, positions);
  vtrans_kernel<<<dim3(80, 32, 2), dim3(32, 8), 0, stream>>>(qkv, vT);
  attn_kernel<<<dim3(8, 32, 2), 256, 0, stream>>>(qkv, vT, obuf);
  // dense GEMM: 128x128 tiles -> 16 x 20 = 320 blocks
  gemm256_kernel<4, 2, false><<<320, 512, 0, stream>>>(obuf, wdt, db, d_out, HIDq, HIDq, 16);
}

// Round 7
// 255.860 us; speedup vs baseline: 1.0374x; 1.0243x over previous
//
#include <hip/hip_runtime.h>
#include <hip/hip_bf16.h>

// Problem constants (PhiAttention: B=2,S=1024,HID=2560,H=32,D=80,ROT=32)
#define Bq 2
#define Sq 1024
#define Tq 2048
#define HIDq 2560
#define Hq 32
#define Dq 80
#define NQKV 7680   // 3*HID

typedef __bf16 bf16x8 __attribute__((ext_vector_type(8)));
typedef float f32x4 __attribute__((ext_vector_type(4)));
typedef float f32x16 __attribute__((ext_vector_type(16)));
typedef unsigned short u16x8 __attribute__((ext_vector_type(8)));
using bf16 = __hip_bfloat16;

__device__ __forceinline__ void gload_lds16(const bf16* g, bf16* l) {
  __builtin_amdgcn_global_load_lds((const __attribute__((address_space(1))) void*)g,
                                   (__attribute__((address_space(3))) void*)l,
                                   16, 0, 0);
}

// ---------------- cast h (fp32 -> bf16) ----------------
__global__ __launch_bounds__(256) void cast_h_kernel(const float* __restrict__ h,
                                                     bf16* __restrict__ hb) {
  int i = (blockIdx.x * 256 + threadIdx.x) * 4;
  float4 v = *(const float4*)(h + i);
  bf16 tmp[4];
  tmp[0] = __float2bfloat16(v.x);
  tmp[1] = __float2bfloat16(v.y);
  tmp[2] = __float2bfloat16(v.z);
  tmp[3] = __float2bfloat16(v.w);
  *(ushort4*)(hb + i) = *(ushort4*)tmp;
}

// ---------------- concat qkv bias ----------------
__global__ __launch_bounds__(256) void bias_concat_kernel(const float* __restrict__ qb,
                                                          const float* __restrict__ kb,
                                                          const float* __restrict__ vb,
                                                          float* __restrict__ bqkv) {
  int i = blockIdx.x * 256 + threadIdx.x;
  if (i < HIDq) bqkv[i] = qb[i];
  else if (i < 2 * HIDq) bqkv[i] = kb[i - HIDq];
  else bqkv[i] = vb[i - 2 * HIDq];
}

// ---------------- transpose-cast weights: wt[n][k] = w[k][n], fp32->bf16 ----------------
__global__ __launch_bounds__(256) void wtrans_kernel(const float* __restrict__ qw,
                                                     const float* __restrict__ kw,
                                                     const float* __restrict__ vw,
                                                     const float* __restrict__ dw,
                                                     bf16* __restrict__ wqkvt,
                                                     bf16* __restrict__ wdt) {
  __shared__ float tile[32][33];
  const int z = blockIdx.z;
  const float* src = (z == 0) ? qw : (z == 1) ? kw : (z == 2) ? vw : dw;
  const int n0 = blockIdx.x * 32;  // src col  (dst row)
  const int k0 = blockIdx.y * 32;  // src row  (dst col)
  const int tx = threadIdx.x, ty = threadIdx.y;
#pragma unroll
  for (int r = 0; r < 4; r++)
    tile[ty + 8 * r][tx] = src[(size_t)(k0 + ty + 8 * r) * HIDq + n0 + tx];
  __syncthreads();
  bf16* dst = (z < 3) ? (wqkvt + (size_t)z * HIDq * HIDq) : wdt;
#pragma unroll
  for (int r = 0; r < 4; r++)
    dst[(size_t)(n0 + ty + 8 * r) * HIDq + k0 + tx] = __float2bfloat16(tile[tx][ty + 8 * r]);
}

// ================= 32x32-MFMA 256x256 ring GEMM (QKV) =================
// C[M][N] = A[M][K] @ Bt[N][K]^T + bias, bf16 out.  8 waves (2m x 4n),
// per-wave 128x64 via mfma_f32_32x32x16_bf16 (4 m-pos x 2 n-pos, acc 8x16 f32).
// BK=32, 3-buffer 96KB LDS ring, counted vmcnt(4), XOR swizzle (both-sides),
// XCD block swizzle, hoisted addressing (ds offsets + global ptrs precomputed).
// LDS read/FLOP = 22.9 B/KF (vs 31 for the 16x16 fragment pattern).
__global__ __launch_bounds__(512, 2) void gemm32_kernel(const bf16* __restrict__ A,
                                                        const bf16* __restrict__ Bt,
                                                        const float* __restrict__ bias,
                                                        bf16* __restrict__ Cout,
                                                        int N, int K, int tM) {
  __shared__ char smem[3 * 32768];  // ring of (A 16K + B 16K)
  const int tid = threadIdx.x;
  const int lane = tid & 63;
  const int ln32 = lane & 31, hi = lane >> 5;
  const int wave = tid >> 6;
  const int wm = wave >> 2;   // 0..1
  const int wn = wave & 3;    // 0..3

  int bid = blockIdx.x, nwg = gridDim.x, swz = bid;
  if ((nwg & 7) == 0) { int cpx = nwg >> 3; swz = (bid & 7) * cpx + (bid >> 3); }
  const int m0 = (swz % tM) * 256;
  const int n0 = (swz / tM) * 256;
  const int NT = K >> 5;  // K/32

  f32x16 acc[4][2];
#pragma unroll
  for (int i = 0; i < 4; ++i)
#pragma unroll
    for (int j = 0; j < 2; ++j)
#pragma unroll
      for (int r = 0; r < 16; ++r) acc[i][j][r] = 0.f;

  // ---- hoisted staging pointers (per-thread global src, wave-uniform LDS dst) ----
  const int Rl0 = tid >> 2;
  const int slot = tid & 3;
  const int wbase = wave * 1024;
  const bf16* gp[4];
  int ldd[4];
#pragma unroll
  for (int c = 0; c < 2; ++c) {
    const int srow = c * 128 + Rl0;
    const int row = srow ^ ((srow >> 2) & 1);   // involution (bit0 ^= bit2)
    const int col8 = slot ^ (row & 3);          // inverse col swizzle
    gp[c]     = A  + (size_t)(m0 + row) * K + col8 * 8;
    gp[2 + c] = Bt + (size_t)(n0 + row) * K + col8 * 8;
    ldd[c] = c * 8192 + wbase;
    ldd[2 + c] = 16384 + c * 8192 + wbase;
  }
  auto STAGE = [&](int t) {
    char* dst = smem + (t % 3) * 32768;
#pragma unroll
    for (int c = 0; c < 4; ++c)
      gload_lds16(gp[c] + t * 32, (bf16*)(dst + ldd[c]));
  };

  // ---- hoisted swizzled ds-read byte offsets ----
  // logical: row (within 256-row panel), 16B col slot = ks*2 + hi
  unsigned offA[4][2], offB[2][2];
#pragma unroll
  for (int i = 0; i < 4; ++i)
#pragma unroll
    for (int ks = 0; ks < 2; ++ks) {
      const int row = wm * 128 + i * 32 + ln32;
      const int colw = ks * 2 + hi;
      offA[i][ks] = ((unsigned)((row ^ ((row >> 2) & 1)) << 6)) |
                    ((unsigned)((colw ^ (row & 3)) << 4));
    }
#pragma unroll
  for (int j = 0; j < 2; ++j)
#pragma unroll
    for (int ks = 0; ks < 2; ++ks) {
      const int row = wn * 64 + j * 32 + ln32;
      const int colw = ks * 2 + hi;
      offB[j][ks] = 16384u + (((unsigned)((row ^ ((row >> 2) & 1)) << 6)) |
                              ((unsigned)((colw ^ (row & 3)) << 4)));
    }

  STAGE(0);
  STAGE(1);
  asm volatile("s_waitcnt vmcnt(4)" ::: "memory");  // tile 0 landed
  __builtin_amdgcn_s_barrier();

  for (int t = 0; t < NT; ++t) {
    char* buf = smem + (t % 3) * 32768;
    if (t + 2 < NT) STAGE(t + 2);

    bf16x8 af[4][2], bfr[2][2];
#pragma unroll
    for (int ks = 0; ks < 2; ++ks) {
#pragma unroll
      for (int j = 0; j < 2; ++j) bfr[j][ks] = *(const bf16x8*)(buf + offB[j][ks]);
#pragma unroll
      for (int i = 0; i < 4; ++i) af[i][ks] = *(const bf16x8*)(buf + offA[i][ks]);
    }
    __builtin_amdgcn_s_setprio(1);
#pragma unroll
    for (int ks = 0; ks < 2; ++ks)
#pragma unroll
      for (int i = 0; i < 4; ++i)
#pragma unroll
        for (int j = 0; j < 2; ++j)
          acc[i][j] = __builtin_amdgcn_mfma_f32_32x32x16_bf16(af[i][ks], bfr[j][ks],
                                                              acc[i][j], 0, 0, 0);
    __builtin_amdgcn_s_setprio(0);

    if (t + 2 < NT) asm volatile("s_waitcnt vmcnt(4)" ::: "memory");
    else            asm volatile("s_waitcnt vmcnt(0)" ::: "memory");
    __builtin_amdgcn_s_barrier();
  }

  // epilogue: C/D map col=lane&31, row=(reg&3)+8*(reg>>2)+4*(lane>>5)  [m74/m101]
#pragma unroll
  for (int j = 0; j < 2; ++j) {
    const int col = n0 + wn * 64 + j * 32 + ln32;
    const float bv = bias[col];
#pragma unroll
    for (int i = 0; i < 4; ++i) {
      const int rowb = m0 + wm * 128 + i * 32 + 4 * hi;
#pragma unroll
      for (int r = 0; r < 16; ++r) {
        const int row = rowb + (r & 3) + 8 * (r >> 2);
        Cout[(size_t)row * N + col] = __float2bfloat16(acc[i][j][r] + bv);
      }
    }
  }
}

// ================= pipelined ring GEMM (dense projection; r6 structure) =================
template <int MFRAG, int NFRAG, bool OUT_BF16>
__global__ __launch_bounds__(512, 4) void gemm256_kernel(const bf16* __restrict__ A,
                                                         const bf16* __restrict__ Bt,
                                                         const float* __restrict__ bias,
                                                         void* __restrict__ Cout,
                                                         int N, int K, int tMc) {
  constexpr int ACALLS = MFRAG / 4;
  constexpr int BCALLS = NFRAG / 2;
  constexpr int APANEL = 8192 * ACALLS;
  constexpr int BUFSZ = APANEL + 8192 * BCALLS;
  __shared__ char smem[3 * BUFSZ];
  const int tid = threadIdx.x;
  const int lane = tid & 63;
  const int ln = lane & 15, lg = lane >> 4;
  const int wave = tid >> 6;
  const int wm = wave >> 2;
  const int wn = wave & 3;

  int bid = blockIdx.x;
  int swz = bid;
  int nwg = gridDim.x;
  if ((nwg & 7) == 0) { int cpx = nwg >> 3; swz = (bid & 7) * cpx + (bid >> 3); }
  const int m0 = (swz % tMc) * (32 * MFRAG);
  const int n0 = (swz / tMc) * (64 * NFRAG);

  const int NT = K >> 5;

  f32x4 acc[MFRAG][NFRAG];
  const f32x4 zz = {0.f, 0.f, 0.f, 0.f};
#pragma unroll
  for (int i = 0; i < MFRAG; ++i)
#pragma unroll
    for (int j = 0; j < NFRAG; ++j) acc[i][j] = zz;

  const int Rl0 = tid >> 2;
  const int slot = tid & 3;
  const int wbase = (tid >> 6) * 1024;

  auto STAGE = [&](int t, int b) {
    const int k0 = t << 5;
    char* Ab = smem + b * BUFSZ;
    char* Bb = Ab + APANEL;
#pragma unroll
    for (int c = 0; c < ACALLS; ++c) {
      const int srow = c * 128 + Rl0;
      const int row = srow ^ ((srow >> 2) & 1);
      const int col8 = slot ^ (row & 3);
      gload_lds16(A + (size_t)(m0 + row) * K + k0 + col8 * 8,
                  (bf16*)(Ab + c * 8192 + wbase));
    }
#pragma unroll
    for (int c = 0; c < BCALLS; ++c) {
      const int srow = c * 128 + Rl0;
      const int row = srow ^ ((srow >> 2) & 1);
      const int col8 = slot ^ (row & 3);
      gload_lds16(Bt + (size_t)(n0 + row) * K + k0 + col8 * 8,
                  (bf16*)(Bb + c * 8192 + wbase));
    }
  };

  auto FRAG = [&](const char* base, int row) -> bf16x8 {
    const unsigned off = ((unsigned)((row ^ ((row >> 2) & 1)) << 6)) |
                         (((unsigned)lg << 4) ^ ((unsigned)(row & 3) << 4));
    return *(const bf16x8*)(base + off);
  };

  auto WAIT_COUNTED = [&]() {
    constexpr int NCALLS = ACALLS + BCALLS;
    if constexpr (NCALLS == 2)      asm volatile("s_waitcnt vmcnt(2)" ::: "memory");
    else if constexpr (NCALLS == 3) asm volatile("s_waitcnt vmcnt(3)" ::: "memory");
    else                            asm volatile("s_waitcnt vmcnt(4)" ::: "memory");
  };

  STAGE(0, 0);
  STAGE(1, 1);
  WAIT_COUNTED();
  __builtin_amdgcn_s_barrier();

  for (int t = 0; t < NT; ++t) {
    const int cb = t % 3;
    const char* Ab = smem + cb * BUFSZ;
    const char* Bb = Ab + APANEL;
    if (t + 2 < NT) STAGE(t + 2, (t + 2) % 3);

    bf16x8 bfr[NFRAG];
#pragma unroll
    for (int j = 0; j < NFRAG; ++j) bfr[j] = FRAG(Bb, wn * (16 * NFRAG) + j * 16 + ln);
#pragma unroll
    for (int ph = 0; ph < ACALLS; ++ph) {
      bf16x8 af[4];
#pragma unroll
      for (int i = 0; i < 4; ++i)
        af[i] = FRAG(Ab, wm * (16 * MFRAG) + (ph * 4 + i) * 16 + ln);
      __builtin_amdgcn_s_setprio(1);
#pragma unroll
      for (int i = 0; i < 4; ++i)
#pragma unroll
        for (int j = 0; j < NFRAG; ++j)
          acc[ph * 4 + i][j] =
              __builtin_amdgcn_mfma_f32_16x16x32_bf16(af[i], bfr[j], acc[ph * 4 + i][j], 0, 0, 0);
      __builtin_amdgcn_s_setprio(0);
    }

    if (t + 2 < NT) WAIT_COUNTED();
    else            asm volatile("s_waitcnt vmcnt(0)" ::: "memory");
    __builtin_amdgcn_s_barrier();
  }

#pragma unroll
  for (int i = 0; i < MFRAG; ++i) {
    const int rowb = m0 + wm * (16 * MFRAG) + i * 16 + lg * 4;
#pragma unroll
    for (int r = 0; r < 4; ++r) {
#pragma unroll
      for (int j = 0; j < NFRAG; ++j) {
        const int col = n0 + wn * (16 * NFRAG) + j * 16 + ln;
        const float v = acc[i][j][r] + bias[col];
        if (OUT_BF16)
          ((bf16*)Cout)[(size_t)(rowb + r) * N + col] = __float2bfloat16(v);
        else
          ((float*)Cout)[(size_t)(rowb + r) * N + col] = v;
      }
    }
  }
}

// ---------------- RoPE on q and k (in-place, bf16) ----------------
__global__ __launch_bounds__(256) void rope_kernel(bf16* __restrict__ qkv,
                                                   const int* __restrict__ positions) {
  int tid = blockIdx.x * 256 + threadIdx.x;  // T*H*16
  int i = tid & 15;
  int h = (tid >> 4) & 31;
  int t = tid >> 9;
  float pos = (float)positions[t];
  float inv = exp2f(-0.83048202372f * (float)i);  // 10000^(-2i/32)
  float ang = pos * inv;
  float s, c;
  sincosf(ang, &s, &c);
  size_t base = (size_t)t * NQKV + h * Dq + i;
  {
    float x1 = __bfloat162float(qkv[base]);
    float x2 = __bfloat162float(qkv[base + 16]);
    qkv[base] = __float2bfloat16(x1 * c - x2 * s);
    qkv[base + 16] = __float2bfloat16(x2 * c + x1 * s);
  }
  base += HIDq;
  {
    float x1 = __bfloat162float(qkv[base]);
    float x2 = __bfloat162float(qkv[base + 16]);
    qkv[base] = __float2bfloat16(x1 * c - x2 * s);
    qkv[base + 16] = __float2bfloat16(x2 * c + x1 * s);
  }
}

// ---------------- V transpose: vT[b][hd][s] = v[b*S+s][hd] ----------------
__global__ __launch_bounds__(256) void vtrans_kernel(const bf16* __restrict__ qkv,
                                                     bf16* __restrict__ vT) {
  __shared__ bf16 tile[32][33];
  const int b = blockIdx.z;
  const int c0 = blockIdx.x * 32;  // hd
  const int s0 = blockIdx.y * 32;  // s
  const int tx = threadIdx.x, ty = threadIdx.y;
#pragma unroll
  for (int r = 0; r < 4; r++)
    tile[ty + 8 * r][tx] = qkv[(size_t)(b * Sq + s0 + ty + 8 * r) * NQKV + 2 * HIDq + c0 + tx];
  __syncthreads();
#pragma unroll
  for (int r = 0; r < 4; r++)
    vT[(size_t)b * HIDq * Sq + (size_t)(c0 + ty + 8 * r) * Sq + s0 + tx] = tile[tx][ty + 8 * r];
}

// ---------------- causal flash attention (balanced, QBLK=64, paired q-tiles) ----
__global__ __launch_bounds__(256) void attn_kernel(const bf16* __restrict__ qkv,
                                                   const bf16* __restrict__ vT,
                                                   bf16* __restrict__ obuf) {
  const int p = blockIdx.x;
  const int h = blockIdx.y;
  const int b = blockIdx.z;
  __shared__ bf16 Ks[64][104];     // pad: 208B rows -> 2-way (free)
  __shared__ bf16 Vt[80][72];      // pad: 144B rows -> 2-way (free)
  __shared__ bf16 Ps[4][16][72];
  const int tid = threadIdx.x;
  const int wave = tid >> 6, lane = tid & 63;
  const int ln = lane & 15, lg = lane >> 4;
  const float scale = 0.1118033988749895f;  // 1/sqrt(80)
  const u16x8 zv = {0, 0, 0, 0, 0, 0, 0, 0};

#pragma unroll
  for (int qsel = 0; qsel < 2; ++qsel) {
    const int qt = qsel ? (15 - p) : p;

    bf16x8 aq[3];
    {
      const size_t qbase = (size_t)(b * Sq + qt * 64 + wave * 16 + ln) * NQKV + h * Dq;
#pragma unroll
      for (int kc = 0; kc < 3; ++kc) {
        const int col = kc * 32 + lg * 8;
        u16x8 v = zv;
        if (col < 80) v = *(const u16x8*)(qkv + qbase + col);
        aq[kc] = *(bf16x8*)&v;
      }
    }

    float mstate[4], lstate[4];
    f32x4 oacc[5];
    const f32x4 zz = {0.f, 0.f, 0.f, 0.f};
#pragma unroll
    for (int r = 0; r < 4; ++r) { mstate[r] = -__builtin_inff(); lstate[r] = 0.f; }
#pragma unroll
    for (int n = 0; n < 5; ++n) oacc[n] = zz;

    for (int j = 0; j <= qt; ++j) {
      const int kv0 = j * 64;
      __syncthreads();
      for (int idx = tid; idx < 64 * 13; idx += 256) {
        int rr = idx / 13, c8 = idx % 13;
        u16x8 val = zv;
        if (c8 < 10)
          val = *(const u16x8*)(qkv + (size_t)(b * Sq + kv0 + rr) * NQKV + HIDq + h * Dq + c8 * 8);
        *(u16x8*)&Ks[rr][c8 * 8] = val;
      }
      for (int idx = tid; idx < 80 * 8; idx += 256) {
        int rr = idx >> 3, c8 = idx & 7;
        *(u16x8*)&Vt[rr][c8 * 8] =
            *(const u16x8*)(vT + (size_t)b * HIDq * Sq + (size_t)(h * Dq + rr) * Sq + kv0 + c8 * 8);
      }
      __syncthreads();

      f32x4 sacc[4];
#pragma unroll
      for (int n = 0; n < 4; ++n) sacc[n] = zz;
#pragma unroll
      for (int kc = 0; kc < 3; ++kc) {
        bf16x8 bk[4];
#pragma unroll
        for (int n = 0; n < 4; ++n) bk[n] = *(const bf16x8*)&Ks[n * 16 + ln][kc * 32 + lg * 8];
#pragma unroll
        for (int n = 0; n < 4; ++n)
          sacc[n] = __builtin_amdgcn_mfma_f32_16x16x32_bf16(aq[kc], bk[n], sacc[n], 0, 0, 0);
      }

      const bool diag = (j == qt);
#pragma unroll
      for (int r = 0; r < 4; ++r) {
        const int qloc = wave * 16 + lg * 4 + r;
        float v[4];
        float vmax = -__builtin_inff();
#pragma unroll
        for (int n = 0; n < 4; ++n) {
          float x = sacc[n][r] * scale;
          if (diag && (n * 16 + ln) > qloc) x = -__builtin_inff();
          v[n] = x;
          vmax = fmaxf(vmax, x);
        }
#pragma unroll
        for (int off = 8; off >= 1; off >>= 1) vmax = fmaxf(vmax, __shfl_xor(vmax, off, 64));
        const float mo = mstate[r];
        const float mn = fmaxf(mo, vmax);
        const float alpha = __expf(mo - mn);
        float psum = 0.f;
#pragma unroll
        for (int n = 0; n < 4; ++n) {
          const float pv = __expf(v[n] - mn);
          psum += pv;
          Ps[wave][lg * 4 + r][n * 16 + ln] = __float2bfloat16(pv);
        }
#pragma unroll
        for (int off = 8; off >= 1; off >>= 1) psum += __shfl_xor(psum, off, 64);
        lstate[r] = lstate[r] * alpha + psum;
        mstate[r] = mn;
#pragma unroll
        for (int n5 = 0; n5 < 5; ++n5) oacc[n5][r] *= alpha;
      }
      asm volatile("s_waitcnt lgkmcnt(0)" ::: "memory");
      __builtin_amdgcn_sched_barrier(0);

#pragma unroll
      for (int kc = 0; kc < 2; ++kc) {
        bf16x8 ap = *(const bf16x8*)&Ps[wave][ln][kc * 32 + lg * 8];
        bf16x8 bv[5];
#pragma unroll
        for (int n = 0; n < 5; ++n) bv[n] = *(const bf16x8*)&Vt[n * 16 + ln][kc * 32 + lg * 8];
#pragma unroll
        for (int n = 0; n < 5; ++n)
          oacc[n] = __builtin_amdgcn_mfma_f32_16x16x32_bf16(ap, bv[n], oacc[n], 0, 0, 0);
      }
    }

#pragma unroll
    for (int r = 0; r < 4; ++r) {
      const float inv = 1.0f / lstate[r];
      const size_t rowbase =
          (size_t)(b * Sq + qt * 64 + wave * 16 + lg * 4 + r) * HIDq + h * Dq;
#pragma unroll
      for (int n5 = 0; n5 < 5; ++n5)
        obuf[rowbase + n5 * 16 + ln] = __float2bfloat16(oacc[n5][r] * inv);
    }
  }
}

// ---------------- launch ----------------
extern "C" void kernel_launch(void* const* d_in, const int* in_sizes, int n_in,
                              void* d_out, int out_size, void* d_ws, size_t ws_size,
                              hipStream_t stream) {
  const float* h = (const float*)d_in[0];
  const float* q_w = (const float*)d_in[3];
  const float* q_b = (const float*)d_in[4];
  const float* k_w = (const float*)d_in[5];
  const float* k_b = (const float*)d_in[6];
  const float* v_w = (const float*)d_in[7];
  const float* v_b = (const float*)d_in[8];
  const float* dw = (const float*)d_in[9];
  const float* db = (const float*)d_in[10];
  const int* positions = (const int*)d_in[11];

  if (ws_size < 94402560ull) return;
  char* ws = (char*)d_ws;
  bf16* hb = (bf16*)(ws);                    // 10,485,760
  bf16* wqkvt = (bf16*)(ws + 10485760);      // 39,321,600
  bf16* wdt = (bf16*)(ws + 49807360);        // 13,107,200
  bf16* qkv = (bf16*)(ws + 62914560);        // 31,457,280
  float* bqkv = (float*)(ws + 94371840);     // 30,720
  bf16* vT = hb;       // h dead after QKV gemm
  bf16* obuf = wqkvt;  // qkv weights dead after QKV gemm

  cast_h_kernel<<<5120, 256, 0, stream>>>(h, hb);
  bias_concat_kernel<<<30, 256, 0, stream>>>(q_b, k_b, v_b, bqkv);
  wtrans_kernel<<<dim3(80, 80, 4), dim3(32, 8), 0, stream>>>(q_w, k_w, v_w, dw, wqkvt, wdt);
  // QKV GEMM: 32x32-MFMA 256x256 tiles -> 8 x 30 = 240 blocks
  gemm32_kernel<<<240, 512, 0, stream>>>(hb, wqkvt, bqkv, qkv, NQKV, HIDq, 8);
  rope_kernel<<<4096, 256, 0, stream>>>(qkv, positions);
  vtrans_kernel<<<dim3(80, 32, 2), dim3(32, 8), 0, stream>>>(qkv, vT);
  attn_kernel<<<dim3(8, 32, 2), 256, 0, stream>>>(qkv, vT, obuf);
  // dense GEMM: 128x128 tiles -> 16 x 20 = 320 blocks
  gemm256_kernel<4, 2, false><<<320, 512, 0, stream>>>(obuf, wdt, db, d_out, HIDq, HIDq, 16);
}

// Round 8
// 237.311 us; speedup vs baseline: 1.1185x; 1.0782x over previous
//
#include <hip/hip_runtime.h>
#include <hip/hip_bf16.h>

// Problem constants (PhiAttention: B=2,S=1024,HID=2560,H=32,D=80,ROT=32)
#define Bq 2
#define Sq 1024
#define Tq 2048
#define HIDq 2560
#define Hq 32
#define Dq 80
#define NQKV 7680   // 3*HID

typedef __bf16 bf16x8 __attribute__((ext_vector_type(8)));
typedef float f32x4 __attribute__((ext_vector_type(4)));
typedef unsigned short u16x8 __attribute__((ext_vector_type(8)));
using bf16 = __hip_bfloat16;

__device__ __forceinline__ void gload_lds16(const bf16* g, bf16* l) {
  __builtin_amdgcn_global_load_lds((const __attribute__((address_space(1))) void*)g,
                                   (__attribute__((address_space(3))) void*)l,
                                   16, 0, 0);
}

// ---------------- cast h (fp32 -> bf16) ----------------
__global__ __launch_bounds__(256) void cast_h_kernel(const float* __restrict__ h,
                                                     bf16* __restrict__ hb) {
  int i = (blockIdx.x * 256 + threadIdx.x) * 4;
  float4 v = *(const float4*)(h + i);
  bf16 tmp[4];
  tmp[0] = __float2bfloat16(v.x);
  tmp[1] = __float2bfloat16(v.y);
  tmp[2] = __float2bfloat16(v.z);
  tmp[3] = __float2bfloat16(v.w);
  *(ushort4*)(hb + i) = *(ushort4*)tmp;
}

// ---------------- concat qkv bias ----------------
__global__ __launch_bounds__(256) void bias_concat_kernel(const float* __restrict__ qb,
                                                          const float* __restrict__ kb,
                                                          const float* __restrict__ vb,
                                                          float* __restrict__ bqkv) {
  int i = blockIdx.x * 256 + threadIdx.x;
  if (i < HIDq) bqkv[i] = qb[i];
  else if (i < 2 * HIDq) bqkv[i] = kb[i - HIDq];
  else bqkv[i] = vb[i - 2 * HIDq];
}

// ---------------- transpose-cast weights: wt[n][k] = w[k][n], fp32->bf16 ----------------
__global__ __launch_bounds__(256) void wtrans_kernel(const float* __restrict__ qw,
                                                     const float* __restrict__ kw,
                                                     const float* __restrict__ vw,
                                                     const float* __restrict__ dw,
                                                     bf16* __restrict__ wqkvt,
                                                     bf16* __restrict__ wdt) {
  __shared__ float tile[32][33];
  const int z = blockIdx.z;
  const float* src = (z == 0) ? qw : (z == 1) ? kw : (z == 2) ? vw : dw;
  const int n0 = blockIdx.x * 32;  // src col  (dst row)
  const int k0 = blockIdx.y * 32;  // src row  (dst col)
  const int tx = threadIdx.x, ty = threadIdx.y;
#pragma unroll
  for (int r = 0; r < 4; r++)
    tile[ty + 8 * r][tx] = src[(size_t)(k0 + ty + 8 * r) * HIDq + n0 + tx];
  __syncthreads();
  bf16* dst = (z < 3) ? (wqkvt + (size_t)z * HIDq * HIDq) : wdt;
#pragma unroll
  for (int r = 0; r < 4; r++)
    dst[(size_t)(n0 + ty + 8 * r) * HIDq + k0 + tx] = __float2bfloat16(tile[tx][ty + 8 * r]);
}

// ================= 9-slot ring 256x256 GEMM, st_16x32 swizzle (m201 layout) =========
// C[M][N] = A[M][K] @ Bt[N][K]^T + bias, bf16 out.  8 waves (2M x 4N), per-wave 128x64.
// BK=64.  Half-tile = 128 rows x 64 k bf16 = 16 KB (128-B rows), 2 gload calls each.
// LDS = 9 slots x 16 KB = 144 KB ring; half H (= 4t+h; h: 0=A-lo 1=A-hi 2=B-lo 3=B-hi)
// lives in slot H mod 9.  Slot's previous occupant H-9 freed one tile earlier.
// Stage 1 half/phase: p0->A-hi(t+1), p1->B-lo(t+1), p2->B-hi(t+1), p3->A-lo(t+2).
// Tile entry: newest stage preceding = H=4t+4 (2 calls) -> s_waitcnt vmcnt(2), never 0
// except last tile.  ONE barrier + ONE counted vmcnt per K=64 (64 MFMA/barrier/wave).
// Swizzle st_16x32: byte ^= ((byte>>9)&1)<<5, applied to gload SOURCE mapping and
// ds_read address (same involution, both-sides rule).
__global__ __launch_bounds__(512, 2) void gemm9s_kernel(const bf16* __restrict__ A,
                                                        const bf16* __restrict__ Bt,
                                                        const float* __restrict__ bias,
                                                        bf16* __restrict__ Cout,
                                                        int N, int K, int tM) {
  __shared__ char smem[9 * 16384];
  const int tid = threadIdx.x;
  const int lane = tid & 63;
  const int ln = lane & 15, lg = lane >> 4;
  const int wave = tid >> 6;
  const int wm = wave >> 2;   // 0..1
  const int wn = wave & 3;    // 0..3

  // XCD-aware bijective block swizzle (grid % 8 == 0)
  int bid = blockIdx.x, nwg = gridDim.x, swz = bid;
  if ((nwg & 7) == 0) { int cpx = nwg >> 3; swz = (bid & 7) * cpx + (bid >> 3); }
  const int m0 = (swz % tM) * 256;
  const int n0 = (swz / tM) * 256;
  const int NT = K >> 6;  // K/64

  f32x4 acc[8][4];
  const f32x4 zz = {0.f, 0.f, 0.f, 0.f};
#pragma unroll
  for (int i = 0; i < 8; ++i)
#pragma unroll
    for (int j = 0; j < 4; ++j) acc[i][j] = zz;

  // ---- staging source mapping (per-thread, hoisted).  Call c covers linear bytes
  // [c*8192 + tid*16, +16) of a 16 KB half; logical byte P = L ^ ((L>>9&1)<<5);
  // row r = P>>7 (128-B rows), k-byte = P&127.
  int srow[2], skel[2];
#pragma unroll
  for (int c = 0; c < 2; ++c) {
    const unsigned L = (unsigned)(c * 8192 + tid * 16);
    const unsigned P = L ^ (((L >> 9) & 1u) << 5);
    srow[c] = (int)(P >> 7);
    skel[c] = (int)((P & 127u) >> 1);
  }
  const int wbase = wave * 1024;

  // stage half H into slot ss.  hh = H&3 (0=A-lo,1=A-hi,2=B-lo,3=B-hi), th = H>>2.
  auto STAGE = [&](int H, int ss) {
    const int hh = H & 3;
    const int th = H >> 2;
    const bf16* mat = (hh < 2) ? A : Bt;
    const int rowbase = (hh < 2) ? (m0 + hh * 128) : (n0 + (hh - 2) * 128);
    char* dst = smem + (ss << 14);
#pragma unroll
    for (int c = 0; c < 2; ++c)
      gload_lds16(mat + (size_t)(rowbase + srow[c]) * K + th * 64 + skel[c],
                  (bf16*)(dst + c * 8192 + wbase));
  };

  // ---- hoisted swizzled ds-read offsets (within a 16 KB half slot) ----
  // A-frag (mh, i): global row = wm*128 + mh*64 + i*16 + ln -> half h = row>>7,
  //   r = row&127, P = r*128 + kh*64 + lg*16.
  unsigned offA[2][4][2];  // [mh][i][kh]
  int     halfA[2][4];
#pragma unroll
  for (int mh = 0; mh < 2; ++mh)
#pragma unroll
    for (int i = 0; i < 4; ++i) {
      const int row = wm * 128 + mh * 64 + i * 16 + ln;
      halfA[mh][i] = row >> 7;
      const int r = row & 127;
#pragma unroll
      for (int kh = 0; kh < 2; ++kh) {
        const unsigned P = (unsigned)(r * 128 + kh * 64 + lg * 16);
        offA[mh][i][kh] = P ^ (((P >> 9) & 1u) << 5);
      }
    }
  unsigned offB[4][2];  // [j][kh]
  int     halfB[4];
#pragma unroll
  for (int j = 0; j < 4; ++j) {
    const int row = wn * 64 + j * 16 + ln;
    halfB[j] = row >> 7;
    const int r = row & 127;
#pragma unroll
    for (int kh = 0; kh < 2; ++kh) {
      const unsigned P = (unsigned)(r * 128 + kh * 64 + lg * 16);
      offB[j][kh] = P ^ (((P >> 9) & 1u) << 5);
    }
  }

  // prologue: stage halves 0..4 into slots 0..4
#pragma unroll
  for (int H = 0; H < 5; ++H) STAGE(H, H);

  int s0 = 0;  // (4t) mod 9
  for (int t = 0; t < NT; ++t) {
    // tile entry: halves 4t..4t+3 must be resident; newest preceding stage = 4t+4.
    if (t + 1 < NT) asm volatile("s_waitcnt vmcnt(2)" ::: "memory");
    else            asm volatile("s_waitcnt vmcnt(0)" ::: "memory");
    __builtin_amdgcn_s_barrier();

    // slot bases for this tile's 4 halves
    int slt[4];
#pragma unroll
    for (int h = 0; h < 4; ++h) { int s = s0 + h; if (s >= 9) s -= 9; slt[h] = s << 14; }

#pragma unroll
    for (int kh = 0; kh < 2; ++kh) {
      bf16x8 bfr[4];
#pragma unroll
      for (int j = 0; j < 4; ++j)
        bfr[j] = *(const bf16x8*)(smem + slt[2 + halfB[j]] + offB[j][kh]);
#pragma unroll
      for (int mh = 0; mh < 2; ++mh) {
        // stage schedule: phase p = kh*2+mh stages half H = 4t + p + 5
        {
          const int p = kh * 2 + mh;
          const int H = 4 * t + p + 5;
          if (H < 4 * NT) {
            int s = s0 + p + 5; if (s >= 9) s -= 9;
            STAGE(H, s);
          }
        }
        bf16x8 af[4];
#pragma unroll
        for (int i = 0; i < 4; ++i)
          af[i] = *(const bf16x8*)(smem + slt[halfA[mh][i]] + offA[mh][i][kh]);
        __builtin_amdgcn_s_setprio(1);
#pragma unroll
        for (int i = 0; i < 4; ++i)
#pragma unroll
          for (int j = 0; j < 4; ++j)
            acc[mh * 4 + i][j] =
                __builtin_amdgcn_mfma_f32_16x16x32_bf16(af[i], bfr[j], acc[mh * 4 + i][j], 0, 0, 0);
        __builtin_amdgcn_s_setprio(0);
      }
    }

    s0 += 4; if (s0 >= 9) s0 -= 9;
  }

  // epilogue
#pragma unroll
  for (int i = 0; i < 8; ++i) {
    const int rowb = m0 + wm * 128 + i * 16 + lg * 4;
#pragma unroll
    for (int r = 0; r < 4; ++r) {
#pragma unroll
      for (int j = 0; j < 4; ++j) {
        const int col = n0 + wn * 64 + j * 16 + ln;
        Cout[(size_t)(rowb + r) * N + col] = __float2bfloat16(acc[i][j][r] + bias[col]);
      }
    }
  }
}

// ================= pipelined ring GEMM (dense projection; r6 structure) =================
template <int MFRAG, int NFRAG, bool OUT_BF16>
__global__ __launch_bounds__(512, 4) void gemm256_kernel(const bf16* __restrict__ A,
                                                         const bf16* __restrict__ Bt,
                                                         const float* __restrict__ bias,
                                                         void* __restrict__ Cout,
                                                         int N, int K, int tMc) {
  constexpr int ACALLS = MFRAG / 4;
  constexpr int BCALLS = NFRAG / 2;
  constexpr int APANEL = 8192 * ACALLS;
  constexpr int BUFSZ = APANEL + 8192 * BCALLS;
  __shared__ char smem[3 * BUFSZ];
  const int tid = threadIdx.x;
  const int lane = tid & 63;
  const int ln = lane & 15, lg = lane >> 4;
  const int wave = tid >> 6;
  const int wm = wave >> 2;
  const int wn = wave & 3;

  int bid = blockIdx.x;
  int swz = bid;
  int nwg = gridDim.x;
  if ((nwg & 7) == 0) { int cpx = nwg >> 3; swz = (bid & 7) * cpx + (bid >> 3); }
  const int m0 = (swz % tMc) * (32 * MFRAG);
  const int n0 = (swz / tMc) * (64 * NFRAG);

  const int NT = K >> 5;

  f32x4 acc[MFRAG][NFRAG];
  const f32x4 zz = {0.f, 0.f, 0.f, 0.f};
#pragma unroll
  for (int i = 0; i < MFRAG; ++i)
#pragma unroll
    for (int j = 0; j < NFRAG; ++j) acc[i][j] = zz;

  const int Rl0 = tid >> 2;
  const int slot = tid & 3;
  const int wbase = (tid >> 6) * 1024;

  auto STAGE = [&](int t, int b) {
    const int k0 = t << 5;
    char* Ab = smem + b * BUFSZ;
    char* Bb = Ab + APANEL;
#pragma unroll
    for (int c = 0; c < ACALLS; ++c) {
      const int srow = c * 128 + Rl0;
      const int row = srow ^ ((srow >> 2) & 1);
      const int col8 = slot ^ (row & 3);
      gload_lds16(A + (size_t)(m0 + row) * K + k0 + col8 * 8,
                  (bf16*)(Ab + c * 8192 + wbase));
    }
#pragma unroll
    for (int c = 0; c < BCALLS; ++c) {
      const int srow = c * 128 + Rl0;
      const int row = srow ^ ((srow >> 2) & 1);
      const int col8 = slot ^ (row & 3);
      gload_lds16(Bt + (size_t)(n0 + row) * K + k0 + col8 * 8,
                  (bf16*)(Bb + c * 8192 + wbase));
    }
  };

  auto FRAG = [&](const char* base, int row) -> bf16x8 {
    const unsigned off = ((unsigned)((row ^ ((row >> 2) & 1)) << 6)) |
                         (((unsigned)lg << 4) ^ ((unsigned)(row & 3) << 4));
    return *(const bf16x8*)(base + off);
  };

  auto WAIT_COUNTED = [&]() {
    constexpr int NCALLS = ACALLS + BCALLS;
    if constexpr (NCALLS == 2)      asm volatile("s_waitcnt vmcnt(2)" ::: "memory");
    else if constexpr (NCALLS == 3) asm volatile("s_waitcnt vmcnt(3)" ::: "memory");
    else                            asm volatile("s_waitcnt vmcnt(4)" ::: "memory");
  };

  STAGE(0, 0);
  STAGE(1, 1);
  WAIT_COUNTED();
  __builtin_amdgcn_s_barrier();

  for (int t = 0; t < NT; ++t) {
    const int cb = t % 3;
    const char* Ab = smem + cb * BUFSZ;
    const char* Bb = Ab + APANEL;
    if (t + 2 < NT) STAGE(t + 2, (t + 2) % 3);

    bf16x8 bfr[NFRAG];
#pragma unroll
    for (int j = 0; j < NFRAG; ++j) bfr[j] = FRAG(Bb, wn * (16 * NFRAG) + j * 16 + ln);
#pragma unroll
    for (int ph = 0; ph < ACALLS; ++ph) {
      bf16x8 af[4];
#pragma unroll
      for (int i = 0; i < 4; ++i)
        af[i] = FRAG(Ab, wm * (16 * MFRAG) + (ph * 4 + i) * 16 + ln);
      __builtin_amdgcn_s_setprio(1);
#pragma unroll
      for (int i = 0; i < 4; ++i)
#pragma unroll
        for (int j = 0; j < NFRAG; ++j)
          acc[ph * 4 + i][j] =
              __builtin_amdgcn_mfma_f32_16x16x32_bf16(af[i], bfr[j], acc[ph * 4 + i][j], 0, 0, 0);
      __builtin_amdgcn_s_setprio(0);
    }

    if (t + 2 < NT) WAIT_COUNTED();
    else            asm volatile("s_waitcnt vmcnt(0)" ::: "memory");
    __builtin_amdgcn_s_barrier();
  }

#pragma unroll
  for (int i = 0; i < MFRAG; ++i) {
    const int rowb = m0 + wm * (16 * MFRAG) + i * 16 + lg * 4;
#pragma unroll
    for (int r = 0; r < 4; ++r) {
#pragma unroll
      for (int j = 0; j < NFRAG; ++j) {
        const int col = n0 + wn * (16 * NFRAG) + j * 16 + ln;
        const float v = acc[i][j][r] + bias[col];
        if (OUT_BF16)
          ((bf16*)Cout)[(size_t)(rowb + r) * N + col] = __float2bfloat16(v);
        else
          ((float*)Cout)[(size_t)(rowb + r) * N + col] = v;
      }
    }
  }
}

// ---------------- RoPE on q and k (in-place, bf16) ----------------
__global__ __launch_bounds__(256) void rope_kernel(bf16* __restrict__ qkv,
                                                   const int* __restrict__ positions) {
  int tid = blockIdx.x * 256 + threadIdx.x;  // T*H*16
  int i = tid & 15;
  int h = (tid >> 4) & 31;
  int t = tid >> 9;
  float pos = (float)positions[t];
  float inv = exp2f(-0.83048202372f * (float)i);  // 10000^(-2i/32)
  float ang = pos * inv;
  float s, c;
  sincosf(ang, &s, &c);
  size_t base = (size_t)t * NQKV + h * Dq + i;
  {
    float x1 = __bfloat162float(qkv[base]);
    float x2 = __bfloat162float(qkv[base + 16]);
    qkv[base] = __float2bfloat16(x1 * c - x2 * s);
    qkv[base + 16] = __float2bfloat16(x2 * c + x1 * s);
  }
  base += HIDq;
  {
    float x1 = __bfloat162float(qkv[base]);
    float x2 = __bfloat162float(qkv[base + 16]);
    qkv[base] = __float2bfloat16(x1 * c - x2 * s);
    qkv[base + 16] = __float2bfloat16(x2 * c + x1 * s);
  }
}

// ---------------- V transpose: vT[b][hd][s] = v[b*S+s][hd] ----------------
__global__ __launch_bounds__(256) void vtrans_kernel(const bf16* __restrict__ qkv,
                                                     bf16* __restrict__ vT) {
  __shared__ bf16 tile[32][33];
  const int b = blockIdx.z;
  const int c0 = blockIdx.x * 32;  // hd
  const int s0 = blockIdx.y * 32;  // s
  const int tx = threadIdx.x, ty = threadIdx.y;
#pragma unroll
  for (int r = 0; r < 4; r++)
    tile[ty + 8 * r][tx] = qkv[(size_t)(b * Sq + s0 + ty + 8 * r) * NQKV + 2 * HIDq + c0 + tx];
  __syncthreads();
#pragma unroll
  for (int r = 0; r < 4; r++)
    vT[(size_t)b * HIDq * Sq + (size_t)(c0 + ty + 8 * r) * Sq + s0 + tx] = tile[tx][ty + 8 * r];
}

// ---------------- causal flash attention (balanced, QBLK=64, paired q-tiles) ----
__global__ __launch_bounds__(256) void attn_kernel(const bf16* __restrict__ qkv,
                                                   const bf16* __restrict__ vT,
                                                   bf16* __restrict__ obuf) {
  const int p = blockIdx.x;
  const int h = blockIdx.y;
  const int b = blockIdx.z;
  __shared__ bf16 Ks[64][104];     // pad: 208B rows -> 2-way (free)
  __shared__ bf16 Vt[80][72];      // pad: 144B rows -> 2-way (free)
  __shared__ bf16 Ps[4][16][72];
  const int tid = threadIdx.x;
  const int wave = tid >> 6, lane = tid & 63;
  const int ln = lane & 15, lg = lane >> 4;
  const float scale = 0.1118033988749895f;  // 1/sqrt(80)
  const u16x8 zv = {0, 0, 0, 0, 0, 0, 0, 0};

#pragma unroll
  for (int qsel = 0; qsel < 2; ++qsel) {
    const int qt = qsel ? (15 - p) : p;

    bf16x8 aq[3];
    {
      const size_t qbase = (size_t)(b * Sq + qt * 64 + wave * 16 + ln) * NQKV + h * Dq;
#pragma unroll
      for (int kc = 0; kc < 3; ++kc) {
        const int col = kc * 32 + lg * 8;
        u16x8 v = zv;
        if (col < 80) v = *(const u16x8*)(qkv + qbase + col);
        aq[kc] = *(bf16x8*)&v;
      }
    }

    float mstate[4], lstate[4];
    f32x4 oacc[5];
    const f32x4 zz = {0.f, 0.f, 0.f, 0.f};
#pragma unroll
    for (int r = 0; r < 4; ++r) { mstate[r] = -__builtin_inff(); lstate[r] = 0.f; }
#pragma unroll
    for (int n = 0; n < 5; ++n) oacc[n] = zz;

    for (int j = 0; j <= qt; ++j) {
      const int kv0 = j * 64;
      __syncthreads();
      for (int idx = tid; idx < 64 * 13; idx += 256) {
        int rr = idx / 13, c8 = idx % 13;
        u16x8 val = zv;
        if (c8 < 10)
          val = *(const u16x8*)(qkv + (size_t)(b * Sq + kv0 + rr) * NQKV + HIDq + h * Dq + c8 * 8);
        *(u16x8*)&Ks[rr][c8 * 8] = val;
      }
      for (int idx = tid; idx < 80 * 8; idx += 256) {
        int rr = idx >> 3, c8 = idx & 7;
        *(u16x8*)&Vt[rr][c8 * 8] =
            *(const u16x8*)(vT + (size_t)b * HIDq * Sq + (size_t)(h * Dq + rr) * Sq + kv0 + c8 * 8);
      }
      __syncthreads();

      f32x4 sacc[4];
#pragma unroll
      for (int n = 0; n < 4; ++n) sacc[n] = zz;
#pragma unroll
      for (int kc = 0; kc < 3; ++kc) {
        bf16x8 bk[4];
#pragma unroll
        for (int n = 0; n < 4; ++n) bk[n] = *(const bf16x8*)&Ks[n * 16 + ln][kc * 32 + lg * 8];
#pragma unroll
        for (int n = 0; n < 4; ++n)
          sacc[n] = __builtin_amdgcn_mfma_f32_16x16x32_bf16(aq[kc], bk[n], sacc[n], 0, 0, 0);
      }

      const bool diag = (j == qt);
#pragma unroll
      for (int r = 0; r < 4; ++r) {
        const int qloc = wave * 16 + lg * 4 + r;
        float v[4];
        float vmax = -__builtin_inff();
#pragma unroll
        for (int n = 0; n < 4; ++n) {
          float x = sacc[n][r] * scale;
          if (diag && (n * 16 + ln) > qloc) x = -__builtin_inff();
          v[n] = x;
          vmax = fmaxf(vmax, x);
        }
#pragma unroll
        for (int off = 8; off >= 1; off >>= 1) vmax = fmaxf(vmax, __shfl_xor(vmax, off, 64));
        const float mo = mstate[r];
        const float mn = fmaxf(mo, vmax);
        const float alpha = __expf(mo - mn);
        float psum = 0.f;
#pragma unroll
        for (int n = 0; n < 4; ++n) {
          const float pv = __expf(v[n] - mn);
          psum += pv;
          Ps[wave][lg * 4 + r][n * 16 + ln] = __float2bfloat16(pv);
        }
#pragma unroll
        for (int off = 8; off >= 1; off >>= 1) psum += __shfl_xor(psum, off, 64);
        lstate[r] = lstate[r] * alpha + psum;
        mstate[r] = mn;
#pragma unroll
        for (int n5 = 0; n5 < 5; ++n5) oacc[n5][r] *= alpha;
      }
      asm volatile("s_waitcnt lgkmcnt(0)" ::: "memory");
      __builtin_amdgcn_sched_barrier(0);

#pragma unroll
      for (int kc = 0; kc < 2; ++kc) {
        bf16x8 ap = *(const bf16x8*)&Ps[wave][ln][kc * 32 + lg * 8];
        bf16x8 bv[5];
#pragma unroll
        for (int n = 0; n < 5; ++n) bv[n] = *(const bf16x8*)&Vt[n * 16 + ln][kc * 32 + lg * 8];
#pragma unroll
        for (int n = 0; n < 5; ++n)
          oacc[n] = __builtin_amdgcn_mfma_f32_16x16x32_bf16(ap, bv[n], oacc[n], 0, 0, 0);
      }
    }

#pragma unroll
    for (int r = 0; r < 4; ++r) {
      const float inv = 1.0f / lstate[r];
      const size_t rowbase =
          (size_t)(b * Sq + qt * 64 + wave * 16 + lg * 4 + r) * HIDq + h * Dq;
#pragma unroll
      for (int n5 = 0; n5 < 5; ++n5)
        obuf[rowbase + n5 * 16 + ln] = __float2bfloat16(oacc[n5][r] * inv);
    }
  }
}

// ---------------- launch ----------------
extern "C" void kernel_launch(void* const* d_in, const int* in_sizes, int n_in,
                              void* d_out, int out_size, void* d_ws, size_t ws_size,
                              hipStream_t stream) {
  const float* h = (const float*)d_in[0];
  const float* q_w = (const float*)d_in[3];
  const float* q_b = (const float*)d_in[4];
  const float* k_w = (const float*)d_in[5];
  const float* k_b = (const float*)d_in[6];
  const float* v_w = (const float*)d_in[7];
  const float* v_b = (const float*)d_in[8];
  const float* dw = (const float*)d_in[9];
  const float* db = (const float*)d_in[10];
  const int* positions = (const int*)d_in[11];

  if (ws_size < 94402560ull) return;
  char* ws = (char*)d_ws;
  bf16* hb = (bf16*)(ws);                    // 10,485,760
  bf16* wqkvt = (bf16*)(ws + 10485760);      // 39,321,600
  bf16* wdt = (bf16*)(ws + 49807360);        // 13,107,200
  bf16* qkv = (bf16*)(ws + 62914560);        // 31,457,280
  float* bqkv = (float*)(ws + 94371840);     // 30,720
  bf16* vT = hb;       // h dead after QKV gemm
  bf16* obuf = wqkvt;  // qkv weights dead after QKV gemm

  cast_h_kernel<<<5120, 256, 0, stream>>>(h, hb);
  bias_concat_kernel<<<30, 256, 0, stream>>>(q_b, k_b, v_b, bqkv);
  wtrans_kernel<<<dim3(80, 80, 4), dim3(32, 8), 0, stream>>>(q_w, k_w, v_w, dw, wqkvt, wdt);
  // QKV GEMM: 9-slot ring 256x256 tiles -> 8 x 30 = 240 blocks
  gemm9s_kernel<<<240, 512, 0, stream>>>(hb, wqkvt, bqkv, qkv, NQKV, HIDq, 8);
  rope_kernel<<<4096, 256, 0, stream>>>(qkv, positions);
  vtrans_kernel<<<dim3(80, 32, 2), dim3(32, 8), 0, stream>>>(qkv, vT);
  attn_kernel<<<dim3(8, 32, 2), 256, 0, stream>>>(qkv, vT, obuf);
  // dense GEMM: 128x128 tiles -> 16 x 20 = 320 blocks
  gemm256_kernel<4, 2, false><<<320, 512, 0, stream>>>(obuf, wdt, db, d_out, HIDq, HIDq, 16);
}